// Round 8
// baseline (376.235 us; speedup 1.0000x reference)
//
#include <hip/hip_runtime.h>
#include <hip/hip_bf16.h>
#include <math.h>

#define BB 4
#define DD 60
#define SS 512
#define FF 158
#define CC 64
#define HH 128
#define FC 222      // F + C
#define G3 384      // 3H
#define NN 2048     // B*S
#define BDN 240     // B*D

typedef _Float16 f16x8 __attribute__((ext_vector_type(8)));
typedef float f32x4 __attribute__((ext_vector_type(4)));

__device__ __forceinline__ float sigmoidf_(float x){ return 1.0f/(1.0f+__expf(-x)); }
__device__ __forceinline__ float tanhf_(float x){
    float e = __expf(-2.0f*fabsf(x));
    float t = (1.0f - e)/(1.0f + e);
    return copysignf(t, x);
}

// ---- prep: wf16 (384x224) xproj, wqkv (192x160) qkv, whh16 (384x128) gru -------------
__global__ void prep_kernel(const float* __restrict__ w_ih,
                            const float* __restrict__ wq, const float* __restrict__ wk,
                            const float* __restrict__ wv, const float* __restrict__ w_hh,
                            _Float16* __restrict__ wf16, _Float16* __restrict__ wqkv,
                            _Float16* __restrict__ whh16){
    int idx = blockIdx.x*256 + threadIdx.x;
    if (idx < 384*224){
        int n = idx / 224, k = idx % 224;
        wf16[idx] = (k < FC) ? (_Float16)w_ih[n*FC + k] : (_Float16)0.0f;
    } else if (idx < 384*224 + 192*160){
        int i2 = idx - 384*224;
        int n = i2 / 160, k = i2 % 160;
        float v = 0.0f;
        if (k < FF){
            if (n < 64)       v = wq[k*CC + n];
            else if (n < 128) v = wk[k*CC + (n-64)];
            else              v = wv[k*CC + (n-128)];
        }
        wqkv[i2] = (_Float16)v;
    } else {
        int i3 = idx - (384*224 + 192*160);
        if (i3 < 384*128)
            whh16[i3] = (_Float16)w_hh[i3];
    }
}

// ---------------- QKV via f16 MFMA: 64 rows/block, 256 thr (4 waves) ------------------
__global__ __launch_bounds__(256) void qkv_kernel(const float* __restrict__ x,
                           const _Float16* __restrict__ wqkv,
                           const float* __restrict__ bq, const float* __restrict__ bk,
                           const float* __restrict__ bv,
                           _Float16* __restrict__ Qh, _Float16* __restrict__ Kh,
                           float* __restrict__ V){
    __shared__ _Float16 xa[5][64][40];   // fragment layout, 25.6 KB
    int tid  = threadIdx.x;
    int lane = tid & 63, wv = tid >> 6;
    int col  = lane & 15, quad = lane >> 4;
    int row0 = blockIdx.x * 64;

    f16x8 bfr[3][5];
    #pragma unroll
    for (int nt = 0; nt < 3; ++nt){
        int n = wv*48 + nt*16 + col;
        #pragma unroll
        for (int kq = 0; kq < 5; ++kq)
            bfr[nt][kq] = *(const f16x8*)&wqkv[n*160 + kq*32 + quad*8];
    }

    for (int i = tid; i < 64*160; i += 256){
        int r = i / 160, k = i % 160;
        float v = (k < FF) ? x[(size_t)(row0 + r)*FF + k] : 0.0f;
        xa[k >> 5][r][k & 31] = (_Float16)v;
    }
    __syncthreads();

    float bias[3];
    #pragma unroll
    for (int nt = 0; nt < 3; ++nt){
        int n = wv*48 + nt*16 + col;
        bias[nt] = (n < 64) ? bq[n] : (n < 128 ? bk[n-64] : bv[n-128]);
    }

    #pragma unroll 1
    for (int mt = 0; mt < 4; ++mt){
        f16x8 a[5];
        #pragma unroll
        for (int kq = 0; kq < 5; ++kq)
            a[kq] = *(const f16x8*)&xa[kq][mt*16 + col][quad*8];
        #pragma unroll
        for (int nt = 0; nt < 3; ++nt){
            f32x4 c = {0.0f, 0.0f, 0.0f, 0.0f};
            #pragma unroll
            for (int kq = 0; kq < 5; ++kq)
                c = __builtin_amdgcn_mfma_f32_16x16x32_f16(a[kq], bfr[nt][kq], c, 0, 0, 0);
            int n = wv*48 + nt*16 + col;
            #pragma unroll
            for (int reg = 0; reg < 4; ++reg){
                int row = row0 + mt*16 + quad*4 + reg;
                float val = c[reg] + bias[nt];
                if (n < 64)       Qh[(size_t)row*CC + n]       = (_Float16)val;
                else if (n < 128) Kh[(size_t)row*CC + (n-64)]  = (_Float16)val;
                else              V [(size_t)row*CC + (n-128)] = val;
            }
        }
    }
}

// ---------------- attention + fused market: one block per bd --------------------------
__global__ __launch_bounds__(512) void attn_kernel(const _Float16* __restrict__ Qh,
                                                   const _Float16* __restrict__ Kh,
                                                   const int* __restrict__ mask,
                                                   const float* __restrict__ V,
                                                   float* __restrict__ market){
    __shared__ _Float16 kf[2][512][32];   // 64 KB
    __shared__ float w_sh[512];
    __shared__ float mk_lds[512];

    int tid  = threadIdx.x;
    int bd   = blockIdx.x;
    int lane = tid & 63, wv = tid >> 6;
    int col  = lane & 15, quad = lane >> 4;

    const _Float16* qb = Qh + (size_t)(bd*SS)*CC;
    const _Float16* kb = Kh + (size_t)(bd*SS)*CC;

    {
        int t = tid;
        w_sh[t] = 0.0f;
        mk_lds[t] = (mask[bd*SS + t] != 0) ? 1.0f : 0.0f;
    }
    for (int i = tid; i < 4096; i += 512){
        int t = i >> 3, ch = i & 7;
        *(f16x8*)&kf[ch >> 2][t][(ch & 3)*8] = *(const f16x8*)&kb[t*CC + ch*8];
    }

    f16x8 a0[4], a1[4];
    #pragma unroll
    for (int af = 0; af < 4; ++af){
        int row = wv*64 + af*16 + col;
        a0[af] = *(const f16x8*)&qb[row*CC + quad*8];
        a1[af] = *(const f16x8*)&qb[row*CC + 32 + quad*8];
    }
    __syncthreads();

    // ---- pass 0: row sums l ----
    float lacc[4][4] = {{0,0,0,0},{0,0,0,0},{0,0,0,0},{0,0,0,0}};
    #pragma unroll 2
    for (int kt = 0; kt < 32; ++kt){
        f16x8 b0 = *(const f16x8*)&kf[0][kt*16 + col][quad*8];
        f16x8 b1 = *(const f16x8*)&kf[1][kt*16 + col][quad*8];
        float mkv = mk_lds[kt*16 + col];
        #pragma unroll
        for (int af = 0; af < 4; ++af){
            f32x4 c = {0.0f, 0.0f, 0.0f, 0.0f};
            c = __builtin_amdgcn_mfma_f32_16x16x32_f16(a0[af], b0, c, 0, 0, 0);
            c = __builtin_amdgcn_mfma_f32_16x16x32_f16(a1[af], b1, c, 0, 0, 0);
            #pragma unroll
            for (int reg = 0; reg < 4; ++reg)
                lacc[af][reg] += __expf(c[reg]*0.125f) * mkv;
        }
    }
    float crv[4][4];
    #pragma unroll
    for (int af = 0; af < 4; ++af){
        #pragma unroll
        for (int reg = 0; reg < 4; ++reg){
            float l = lacc[af][reg];
            l += __shfl_xor(l, 1, 64);
            l += __shfl_xor(l, 2, 64);
            l += __shfl_xor(l, 4, 64);
            l += __shfl_xor(l, 8, 64);
            int row = wv*64 + af*16 + quad*4 + reg;
            crv[af][reg] = mk_lds[row] / l;
        }
    }

    // ---- pass 1: accumulate W columns ----
    #pragma unroll 2
    for (int kt = 0; kt < 32; ++kt){
        f16x8 b0 = *(const f16x8*)&kf[0][kt*16 + col][quad*8];
        f16x8 b1 = *(const f16x8*)&kf[1][kt*16 + col][quad*8];
        float s = 0.0f;
        #pragma unroll
        for (int af = 0; af < 4; ++af){
            f32x4 c = {0.0f, 0.0f, 0.0f, 0.0f};
            c = __builtin_amdgcn_mfma_f32_16x16x32_f16(a0[af], b0, c, 0, 0, 0);
            c = __builtin_amdgcn_mfma_f32_16x16x32_f16(a1[af], b1, c, 0, 0, 0);
            #pragma unroll
            for (int reg = 0; reg < 4; ++reg)
                s = fmaf(__expf(c[reg]*0.125f), crv[af][reg], s);
        }
        s += __shfl_xor(s, 16, 64);
        s += __shfl_xor(s, 32, 64);
        if (quad == 0)
            atomicAdd(&w_sh[kt*16 + col], s);
    }
    __syncthreads();   // w_sh final; all kf reads complete -> safe to reuse kf as scratch

    // ---- fused market ----
    float* msum = (float*)kf;   // scratch in dead K region
    {
        int c = tid & 63, grp = tid >> 6;
        const float* vb = V + (size_t)(bd*SS)*CC;
        float acc = 0.0f;
        int t0 = grp*64;
        #pragma unroll 4
        for (int t = t0; t < t0 + 64; ++t)
            acc = fmaf(w_sh[t]*mk_lds[t], vb[(size_t)t*CC + c], acc);
        msum[grp*64 + c] = acc;
    }
    __syncthreads();
    if (tid < 64){
        float s = 0.0f;
        #pragma unroll
        for (int g = 0; g < 8; ++g) s += msum[g*64 + tid];
        float cnt = 0.0f;
        #pragma unroll
        for (int j = 0; j < 8; ++j) cnt += mk_lds[tid + 64*j];
        #pragma unroll
        for (int o = 1; o < 64; o <<= 1) cnt += __shfl_xor(cnt, o, 64);
        market[bd*CC + tid] = s / fmaxf(cnt, 1.0f);
    }
}

// ---------------- fused LN + x_proj f16 MFMA GEMM -------------------------------------
__global__ __launch_bounds__(512, 2) void xproj_kernel(const float* __restrict__ x,
                             const float* __restrict__ market,
                             const float* __restrict__ ln_g, const float* __restrict__ ln_b,
                             const _Float16* __restrict__ wf16, const float* __restrict__ b_ih,
                             _Float16* __restrict__ XP){
    __shared__ _Float16 aug[7][64][32];   // 28 KB
    int tid  = threadIdx.x;
    int lane = tid & 63, wv = tid >> 6;
    int col  = lane & 15, quad = lane >> 4;
    int row0 = blockIdx.x * 64;

    f16x8 bfr[3][7];
    #pragma unroll
    for (int nt = 0; nt < 3; ++nt){
        int n = wv*48 + nt*16 + col;
        #pragma unroll
        for (int kq = 0; kq < 7; ++kq)
            bfr[nt][kq] = *(const f16x8*)&wf16[n*224 + kq*32 + quad*8];
    }

    {
        int wrow = wv*8 + (lane >> 3);
        int g    = lane & 7;
        int row  = row0 + wrow;
        int d = row / NN, n = row % NN;
        int b = n >> 9, s = n & 511;
        const float* xr = &x[((size_t)((b*DD + d)*SS) + s)*FF];
        const float* mr = &market[(b*DD + d)*CC];
        float v[28];
        float sum = 0.0f, sq = 0.0f;
        #pragma unroll
        for (int j = 0; j < 28; ++j){
            int f = g + 8*j;
            float vv = 0.0f;
            if (f < FF) vv = xr[f];
            else if (f < FC) vv = mr[f - FF];
            v[j] = vv;
            sum += vv; sq += vv*vv;
        }
        sum += __shfl_xor(sum,1,64); sq += __shfl_xor(sq,1,64);
        sum += __shfl_xor(sum,2,64); sq += __shfl_xor(sq,2,64);
        sum += __shfl_xor(sum,4,64); sq += __shfl_xor(sq,4,64);
        float mu   = sum * (1.0f/222.0f);
        float var  = sq * (1.0f/222.0f) - mu*mu;
        float rstd = rsqrtf(var + 1e-5f);
        #pragma unroll
        for (int j = 0; j < 28; ++j){
            int f = g + 8*j;
            float val = (f < FC) ? ((v[j]-mu)*rstd*ln_g[f] + ln_b[f]) : 0.0f;
            aug[f>>5][wrow][f&31] = (_Float16)val;
        }
    }
    __syncthreads();

    float bias[3];
    #pragma unroll
    for (int nt = 0; nt < 3; ++nt) bias[nt] = b_ih[wv*48 + nt*16 + col];
    #pragma unroll 1
    for (int mt = 0; mt < 4; ++mt){
        f16x8 a[7];
        #pragma unroll
        for (int kq = 0; kq < 7; ++kq)
            a[kq] = *(const f16x8*)&aug[kq][mt*16 + col][quad*8];
        #pragma unroll
        for (int nt = 0; nt < 3; ++nt){
            f32x4 c = {0.0f, 0.0f, 0.0f, 0.0f};
            #pragma unroll
            for (int kq = 0; kq < 7; ++kq)
                c = __builtin_amdgcn_mfma_f32_16x16x32_f16(a[kq], bfr[nt][kq], c, 0, 0, 0);
            int nn = wv*48 + nt*16 + col;
            #pragma unroll
            for (int reg = 0; reg < 4; ++reg){
                int m = quad*4 + reg;
                XP[(size_t)(row0 + mt*16 + m)*G3 + nn] = (_Float16)(c[reg] + bias[nt]);
            }
        }
    }
}

// ---------------- persistent GRU: 1 barrier/step, depth-2 XP prefetch -----------------
// 512 blocks x 256 thr (4 waves), 4 seqs/block. Wave wv owns gate columns
// cc in [wv*32, wv*32+32). hp handoff: same-wave LDS, b128 writes (hp_sh[..][32][4]).
// XP loads for day d+2 issue at top of step d (double reg buffer) -> ~2 steps of
// slack vs ~900-cyc HBM latency.
__global__ __launch_bounds__(256, 2) void gru_kernel(const _Float16* __restrict__ XP,
                                                     const _Float16* __restrict__ whh16,
                                                     const float* __restrict__ b_hh,
                                                     const float* __restrict__ w1, const float* __restrict__ b1,
                                                     const float* __restrict__ w2, const float* __restrict__ b2,
                                                     float* __restrict__ out){
    __shared__ _Float16 hfrag[2][4][16][32];  // 8 KB, MFMA-A fragment layout, dbuf
    __shared__ float hp_sh[4][3][32][4];      // [wave][gate][u][seq] : 6 KB, b128 rows
    __shared__ float h_f32[4][132];           // for head

    int tid  = threadIdx.x;
    int lane = tid & 63, wv = tid >> 6;
    int col  = lane & 15, quad = lane >> 4;
    int row0 = blockIdx.x * 4;

    for (int i = tid; i < 2*4*16*32; i += 256) ((_Float16*)hfrag)[i] = (_Float16)0.0f;

    // B fragments: 3 gates x 2 halves x 4 kq; n = g*128 + wv*32 + half*16 + col
    f16x8 bfr[3][2][4];
    #pragma unroll
    for (int g = 0; g < 3; ++g){
        #pragma unroll
        for (int hf = 0; hf < 2; ++hf){
            int n = g*128 + wv*32 + hf*16 + col;
            #pragma unroll
            for (int kq = 0; kq < 4; ++kq)
                bfr[g][hf][kq] = *(const f16x8*)&whh16[(size_t)n*HH + kq*32 + quad*8];
        }
    }

    int u  = lane & 31;
    int cc = wv*32 + u;
    int sb = lane >> 5;   // seq = j*2 + sb
    float bh0 = b_hh[cc], bh1 = b_hh[128 + cc], bh2 = b_hh[256 + cc];

    float hcur[2] = {0.0f, 0.0f};
    // depth-2 prefetch buffers: xb[p] holds day (d) for p = d&1
    float xb[2][2][3];
    #pragma unroll
    for (int p = 0; p < 2; ++p){
        #pragma unroll
        for (int j = 0; j < 2; ++j){
            int seq = j*2 + sb;
            const _Float16* base = XP + ((size_t)p*NN + row0 + seq)*G3 + cc;
            xb[p][j][0] = (float)base[0];
            xb[p][j][1] = (float)base[128];
            xb[p][j][2] = (float)base[256];
        }
    }
    __syncthreads();

    for (int d = 0; d < DD; ++d){
        int p = d & 1;
        // consume this step's inputs into locals, then re-arm the buffer for d+2
        float xcur[2][3];
        #pragma unroll
        for (int j = 0; j < 2; ++j){
            xcur[j][0] = xb[p][j][0];
            xcur[j][1] = xb[p][j][1];
            xcur[j][2] = xb[p][j][2];
        }
        {
            int dn = (d + 2 < DD) ? d + 2 : d;   // clamped dummy reload at tail
            #pragma unroll
            for (int j = 0; j < 2; ++j){
                int seq = j*2 + sb;
                const _Float16* base = XP + ((size_t)dn*NN + row0 + seq)*G3 + cc;
                xb[p][j][0] = (float)base[0];
                xb[p][j][1] = (float)base[128];
                xb[p][j][2] = (float)base[256];
            }
        }
        // A fragments from h (written at step d-1 into buffer p)
        f16x8 a[4];
        #pragma unroll
        for (int kq = 0; kq < 4; ++kq)
            a[kq] = *(const f16x8*)&hfrag[p][kq][col][quad*8];
        #pragma unroll
        for (int g = 0; g < 3; ++g){
            #pragma unroll
            for (int hf = 0; hf < 2; ++hf){
                f32x4 c = {0.0f, 0.0f, 0.0f, 0.0f};
                #pragma unroll
                for (int kq = 0; kq < 4; ++kq)
                    c = __builtin_amdgcn_mfma_f32_16x16x32_f16(a[kq], bfr[g][hf][kq], c, 0, 0, 0);
                if (quad == 0)
                    *(f32x4*)&hp_sh[wv][g][hf*16 + col][0] = c;   // one b128 store
            }
        }
        // gates: same-wave LDS dependency only (no barrier)
        #pragma unroll
        for (int j = 0; j < 2; ++j){
            int seq = j*2 + sb;
            float hr = hp_sh[wv][0][u][seq] + bh0;
            float hz = hp_sh[wv][1][u][seq] + bh1;
            float hn = hp_sh[wv][2][u][seq] + bh2;
            float r  = sigmoidf_(xcur[j][0] + hr);
            float z  = sigmoidf_(xcur[j][1] + hz);
            float n  = tanhf_(xcur[j][2] + r*hn);
            float hnew = (1.0f - z)*n + z*hcur[j];
            hcur[j] = hnew;
            hfrag[1 - p][wv][seq][u] = (_Float16)hnew;
        }
        __syncthreads();
    }

    #pragma unroll
    for (int j = 0; j < 2; ++j){
        int seq = j*2 + sb;
        h_f32[seq][cc] = hcur[j];
    }
    __syncthreads();

    if (tid < 64){
        int c2 = tid;
        #pragma unroll 1
        for (int r = 0; r < 4; ++r){
            float a0 = 0.0f, a1 = 0.0f;
            #pragma unroll 8
            for (int k = 0; k < 64; ++k){
                a0 = fmaf(h_f32[r][k],      w1[k*64 + c2],        a0);
                a1 = fmaf(h_f32[r][64 + k], w1[(64 + k)*64 + c2], a1);
            }
            float hid = fmaxf(a0 + a1 + b1[c2], 0.0f);
            float o = hid * w2[c2];
            #pragma unroll
            for (int off = 1; off < 64; off <<= 1) o += __shfl_xor(o, off, 64);
            if (c2 == 0) out[row0 + r] = o + b2[0];
        }
    }
}

extern "C" void kernel_launch(void* const* d_in, const int* in_sizes, int n_in,
                              void* d_out, int out_size, void* d_ws, size_t ws_size,
                              hipStream_t stream) {
    const float* x    = (const float*)d_in[0];
    const int*   mask = (const int*)d_in[1];
    const float* wq   = (const float*)d_in[2];
    const float* bq   = (const float*)d_in[3];
    const float* wk   = (const float*)d_in[4];
    const float* bk   = (const float*)d_in[5];
    const float* wv   = (const float*)d_in[6];
    const float* bv   = (const float*)d_in[7];
    const float* ln_g = (const float*)d_in[8];
    const float* ln_b = (const float*)d_in[9];
    const float* w_ih = (const float*)d_in[10];
    const float* w_hh = (const float*)d_in[11];
    const float* b_ih = (const float*)d_in[12];
    const float* b_hh = (const float*)d_in[13];
    const float* w1   = (const float*)d_in[14];
    const float* b1   = (const float*)d_in[15];
    const float* w2   = (const float*)d_in[16];
    const float* b2   = (const float*)d_in[17];

    float* ws = (float*)d_ws;
    // phase 1 (f32 index units):
    _Float16* Qh  = (_Float16*)ws;                    // f16 [0, 3,932,160)
    _Float16* Kh  = (_Float16*)(ws + 3932160);        // f16 [3,932,160, 7,864,320)
    float*    V   = ws + 7864320;                     // f32 [7,864,320, 15,728,640)
    // phase 2: XP aliases the dead Q/K/V region
    _Float16* XP  = (_Float16*)ws;                    // f16 [0, 23,592,960)
    float* market = ws + 23592960;                    //    15,360 f32
    _Float16* wf16 = (_Float16*)(ws + 23608320);      //    86,016 f16
    _Float16* wqkv = (_Float16*)(ws + 23651328);      //    30,720 f16
    _Float16* whh16= (_Float16*)(ws + 23666688);      //    49,152 f16
    // total ~94.8 MB

    prep_kernel<<<648, 256, 0, stream>>>(w_ih, wq, wk, wv, w_hh, wf16, wqkv, whh16);
    qkv_kernel<<<1920, 256, 0, stream>>>(x, wqkv, bq, bk, bv, Qh, Kh, V);
    attn_kernel<<<240, 512, 0, stream>>>(Qh, Kh, mask, V, market);
    xproj_kernel<<<1920, 512, 0, stream>>>(x, market, ln_g, ln_b, wf16, b_ih, XP);
    gru_kernel<<<512, 256, 0, stream>>>(XP, whh16, b_hh, w1, b1, w2, b2, (float*)d_out);
}

// Round 9
// 367.446 us; speedup vs baseline: 1.0239x; 1.0239x over previous
//
#include <hip/hip_runtime.h>
#include <hip/hip_bf16.h>
#include <math.h>

#define BB 4
#define DD 60
#define SS 512
#define FF 158
#define CC 64
#define HH 128
#define FC 222      // F + C
#define G3 384      // 3H
#define NN 2048     // B*S
#define BDN 240     // B*D

typedef _Float16 f16x8 __attribute__((ext_vector_type(8)));
typedef float f32x4 __attribute__((ext_vector_type(4)));

__device__ __forceinline__ float sigmoidf_(float x){ return 1.0f/(1.0f+__expf(-x)); }
__device__ __forceinline__ float tanhf_(float x){
    float e = __expf(-2.0f*fabsf(x));
    float t = (1.0f - e)/(1.0f + e);
    return copysignf(t, x);
}

// ---- prep: wf16 (384x224) xproj, wqkv (192x160) qkv, whh16 (384x128) gru -------------
__global__ void prep_kernel(const float* __restrict__ w_ih,
                            const float* __restrict__ wq, const float* __restrict__ wk,
                            const float* __restrict__ wv, const float* __restrict__ w_hh,
                            _Float16* __restrict__ wf16, _Float16* __restrict__ wqkv,
                            _Float16* __restrict__ whh16){
    int idx = blockIdx.x*256 + threadIdx.x;
    if (idx < 384*224){
        int n = idx / 224, k = idx % 224;
        wf16[idx] = (k < FC) ? (_Float16)w_ih[n*FC + k] : (_Float16)0.0f;
    } else if (idx < 384*224 + 192*160){
        int i2 = idx - 384*224;
        int n = i2 / 160, k = i2 % 160;
        float v = 0.0f;
        if (k < FF){
            if (n < 64)       v = wq[k*CC + n];
            else if (n < 128) v = wk[k*CC + (n-64)];
            else              v = wv[k*CC + (n-128)];
        }
        wqkv[i2] = (_Float16)v;
    } else {
        int i3 = idx - (384*224 + 192*160);
        if (i3 < 384*128)
            whh16[i3] = (_Float16)w_hh[i3];
    }
}

// ---------------- QKV via f16 MFMA: 64 rows/block, 256 thr (4 waves) ------------------
__global__ __launch_bounds__(256) void qkv_kernel(const float* __restrict__ x,
                           const _Float16* __restrict__ wqkv,
                           const float* __restrict__ bq, const float* __restrict__ bk,
                           const float* __restrict__ bv,
                           _Float16* __restrict__ Qh, _Float16* __restrict__ Kh,
                           float* __restrict__ V){
    __shared__ _Float16 xa[5][64][40];   // fragment layout, 25.6 KB
    int tid  = threadIdx.x;
    int lane = tid & 63, wv = tid >> 6;
    int col  = lane & 15, quad = lane >> 4;
    int row0 = blockIdx.x * 64;

    f16x8 bfr[3][5];
    #pragma unroll
    for (int nt = 0; nt < 3; ++nt){
        int n = wv*48 + nt*16 + col;
        #pragma unroll
        for (int kq = 0; kq < 5; ++kq)
            bfr[nt][kq] = *(const f16x8*)&wqkv[n*160 + kq*32 + quad*8];
    }

    for (int i = tid; i < 64*160; i += 256){
        int r = i / 160, k = i % 160;
        float v = (k < FF) ? x[(size_t)(row0 + r)*FF + k] : 0.0f;
        xa[k >> 5][r][k & 31] = (_Float16)v;
    }
    __syncthreads();

    float bias[3];
    #pragma unroll
    for (int nt = 0; nt < 3; ++nt){
        int n = wv*48 + nt*16 + col;
        bias[nt] = (n < 64) ? bq[n] : (n < 128 ? bk[n-64] : bv[n-128]);
    }

    #pragma unroll 1
    for (int mt = 0; mt < 4; ++mt){
        f16x8 a[5];
        #pragma unroll
        for (int kq = 0; kq < 5; ++kq)
            a[kq] = *(const f16x8*)&xa[kq][mt*16 + col][quad*8];
        #pragma unroll
        for (int nt = 0; nt < 3; ++nt){
            f32x4 c = {0.0f, 0.0f, 0.0f, 0.0f};
            #pragma unroll
            for (int kq = 0; kq < 5; ++kq)
                c = __builtin_amdgcn_mfma_f32_16x16x32_f16(a[kq], bfr[nt][kq], c, 0, 0, 0);
            int n = wv*48 + nt*16 + col;
            #pragma unroll
            for (int reg = 0; reg < 4; ++reg){
                int row = row0 + mt*16 + quad*4 + reg;
                float val = c[reg] + bias[nt];
                if (n < 64)       Qh[(size_t)row*CC + n]       = (_Float16)val;
                else if (n < 128) Kh[(size_t)row*CC + (n-64)]  = (_Float16)val;
                else              V [(size_t)row*CC + (n-128)] = val;
            }
        }
    }
}

// ---------------- attention + fused market: one block per bd --------------------------
__global__ __launch_bounds__(512) void attn_kernel(const _Float16* __restrict__ Qh,
                                                   const _Float16* __restrict__ Kh,
                                                   const int* __restrict__ mask,
                                                   const float* __restrict__ V,
                                                   float* __restrict__ market){
    __shared__ _Float16 kf[2][512][32];   // 64 KB
    __shared__ float w_sh[512];
    __shared__ float mk_lds[512];

    int tid  = threadIdx.x;
    int bd   = blockIdx.x;
    int lane = tid & 63, wv = tid >> 6;
    int col  = lane & 15, quad = lane >> 4;

    const _Float16* qb = Qh + (size_t)(bd*SS)*CC;
    const _Float16* kb = Kh + (size_t)(bd*SS)*CC;

    {
        int t = tid;
        w_sh[t] = 0.0f;
        mk_lds[t] = (mask[bd*SS + t] != 0) ? 1.0f : 0.0f;
    }
    for (int i = tid; i < 4096; i += 512){
        int t = i >> 3, ch = i & 7;
        *(f16x8*)&kf[ch >> 2][t][(ch & 3)*8] = *(const f16x8*)&kb[t*CC + ch*8];
    }

    f16x8 a0[4], a1[4];
    #pragma unroll
    for (int af = 0; af < 4; ++af){
        int row = wv*64 + af*16 + col;
        a0[af] = *(const f16x8*)&qb[row*CC + quad*8];
        a1[af] = *(const f16x8*)&qb[row*CC + 32 + quad*8];
    }
    __syncthreads();

    // ---- pass 0: row sums l ----
    float lacc[4][4] = {{0,0,0,0},{0,0,0,0},{0,0,0,0},{0,0,0,0}};
    #pragma unroll 2
    for (int kt = 0; kt < 32; ++kt){
        f16x8 b0 = *(const f16x8*)&kf[0][kt*16 + col][quad*8];
        f16x8 b1 = *(const f16x8*)&kf[1][kt*16 + col][quad*8];
        float mkv = mk_lds[kt*16 + col];
        #pragma unroll
        for (int af = 0; af < 4; ++af){
            f32x4 c = {0.0f, 0.0f, 0.0f, 0.0f};
            c = __builtin_amdgcn_mfma_f32_16x16x32_f16(a0[af], b0, c, 0, 0, 0);
            c = __builtin_amdgcn_mfma_f32_16x16x32_f16(a1[af], b1, c, 0, 0, 0);
            #pragma unroll
            for (int reg = 0; reg < 4; ++reg)
                lacc[af][reg] += __expf(c[reg]*0.125f) * mkv;
        }
    }
    float crv[4][4];
    #pragma unroll
    for (int af = 0; af < 4; ++af){
        #pragma unroll
        for (int reg = 0; reg < 4; ++reg){
            float l = lacc[af][reg];
            l += __shfl_xor(l, 1, 64);
            l += __shfl_xor(l, 2, 64);
            l += __shfl_xor(l, 4, 64);
            l += __shfl_xor(l, 8, 64);
            int row = wv*64 + af*16 + quad*4 + reg;
            crv[af][reg] = mk_lds[row] / l;
        }
    }

    // ---- pass 1: accumulate W columns ----
    #pragma unroll 2
    for (int kt = 0; kt < 32; ++kt){
        f16x8 b0 = *(const f16x8*)&kf[0][kt*16 + col][quad*8];
        f16x8 b1 = *(const f16x8*)&kf[1][kt*16 + col][quad*8];
        float s = 0.0f;
        #pragma unroll
        for (int af = 0; af < 4; ++af){
            f32x4 c = {0.0f, 0.0f, 0.0f, 0.0f};
            c = __builtin_amdgcn_mfma_f32_16x16x32_f16(a0[af], b0, c, 0, 0, 0);
            c = __builtin_amdgcn_mfma_f32_16x16x32_f16(a1[af], b1, c, 0, 0, 0);
            #pragma unroll
            for (int reg = 0; reg < 4; ++reg)
                s = fmaf(__expf(c[reg]*0.125f), crv[af][reg], s);
        }
        s += __shfl_xor(s, 16, 64);
        s += __shfl_xor(s, 32, 64);
        if (quad == 0)
            atomicAdd(&w_sh[kt*16 + col], s);
    }
    __syncthreads();   // w_sh final; kf reads complete -> reuse kf as scratch

    // ---- fused market ----
    float* msum = (float*)kf;
    {
        int c = tid & 63, grp = tid >> 6;
        const float* vb = V + (size_t)(bd*SS)*CC;
        float acc = 0.0f;
        int t0 = grp*64;
        #pragma unroll 4
        for (int t = t0; t < t0 + 64; ++t)
            acc = fmaf(w_sh[t]*mk_lds[t], vb[(size_t)t*CC + c], acc);
        msum[grp*64 + c] = acc;
    }
    __syncthreads();
    if (tid < 64){
        float s = 0.0f;
        #pragma unroll
        for (int g = 0; g < 8; ++g) s += msum[g*64 + tid];
        float cnt = 0.0f;
        #pragma unroll
        for (int j = 0; j < 8; ++j) cnt += mk_lds[tid + 64*j];
        #pragma unroll
        for (int o = 1; o < 64; o <<= 1) cnt += __shfl_xor(cnt, o, 64);
        market[bd*CC + tid] = s / fmaxf(cnt, 1.0f);
    }
}

// ---------------- fused LN + x_proj f16 MFMA GEMM -------------------------------------
__global__ __launch_bounds__(512, 2) void xproj_kernel(const float* __restrict__ x,
                             const float* __restrict__ market,
                             const float* __restrict__ ln_g, const float* __restrict__ ln_b,
                             const _Float16* __restrict__ wf16, const float* __restrict__ b_ih,
                             _Float16* __restrict__ XP){
    __shared__ _Float16 aug[7][64][32];   // 28 KB
    int tid  = threadIdx.x;
    int lane = tid & 63, wv = tid >> 6;
    int col  = lane & 15, quad = lane >> 4;
    int row0 = blockIdx.x * 64;

    f16x8 bfr[3][7];
    #pragma unroll
    for (int nt = 0; nt < 3; ++nt){
        int n = wv*48 + nt*16 + col;
        #pragma unroll
        for (int kq = 0; kq < 7; ++kq)
            bfr[nt][kq] = *(const f16x8*)&wf16[n*224 + kq*32 + quad*8];
    }

    {
        int wrow = wv*8 + (lane >> 3);
        int g    = lane & 7;
        int row  = row0 + wrow;
        int d = row / NN, n = row % NN;
        int b = n >> 9, s = n & 511;
        const float* xr = &x[((size_t)((b*DD + d)*SS) + s)*FF];
        const float* mr = &market[(b*DD + d)*CC];
        float v[28];
        float sum = 0.0f, sq = 0.0f;
        #pragma unroll
        for (int j = 0; j < 28; ++j){
            int f = g + 8*j;
            float vv = 0.0f;
            if (f < FF) vv = xr[f];
            else if (f < FC) vv = mr[f - FF];
            v[j] = vv;
            sum += vv; sq += vv*vv;
        }
        sum += __shfl_xor(sum,1,64); sq += __shfl_xor(sq,1,64);
        sum += __shfl_xor(sum,2,64); sq += __shfl_xor(sq,2,64);
        sum += __shfl_xor(sum,4,64); sq += __shfl_xor(sq,4,64);
        float mu   = sum * (1.0f/222.0f);
        float var  = sq * (1.0f/222.0f) - mu*mu;
        float rstd = rsqrtf(var + 1e-5f);
        #pragma unroll
        for (int j = 0; j < 28; ++j){
            int f = g + 8*j;
            float val = (f < FC) ? ((v[j]-mu)*rstd*ln_g[f] + ln_b[f]) : 0.0f;
            aug[f>>5][wrow][f&31] = (_Float16)val;
        }
    }
    __syncthreads();

    float bias[3];
    #pragma unroll
    for (int nt = 0; nt < 3; ++nt) bias[nt] = b_ih[wv*48 + nt*16 + col];
    #pragma unroll 1
    for (int mt = 0; mt < 4; ++mt){
        f16x8 a[7];
        #pragma unroll
        for (int kq = 0; kq < 7; ++kq)
            a[kq] = *(const f16x8*)&aug[kq][mt*16 + col][quad*8];
        #pragma unroll
        for (int nt = 0; nt < 3; ++nt){
            f32x4 c = {0.0f, 0.0f, 0.0f, 0.0f};
            #pragma unroll
            for (int kq = 0; kq < 7; ++kq)
                c = __builtin_amdgcn_mfma_f32_16x16x32_f16(a[kq], bfr[nt][kq], c, 0, 0, 0);
            int nn = wv*48 + nt*16 + col;
            #pragma unroll
            for (int reg = 0; reg < 4; ++reg){
                int m = quad*4 + reg;
                XP[(size_t)(row0 + mt*16 + m)*G3 + nn] = (_Float16)(c[reg] + bias[nt]);
            }
        }
    }
}

// ---------------- persistent GRU: 1 barrier/step, chunked XP preload ------------------
// 512 blocks x 256 thr (4 waves), 4 seqs/block. Wave wv owns gate columns
// cc in [wv*32, wv*32+32). hp handoff: r7 conflict-free b32 layout (same-wave LDS).
// XP: 10-day register buffer (60 f32/thread); refilled at cs==9 AFTER consumption,
// so the barrier vmcnt(0) drain is paid once per 10 steps instead of every step.
__global__ __launch_bounds__(256, 2) void gru_kernel(const _Float16* __restrict__ XP,
                                                     const _Float16* __restrict__ whh16,
                                                     const float* __restrict__ b_hh,
                                                     const float* __restrict__ w1, const float* __restrict__ b1,
                                                     const float* __restrict__ w2, const float* __restrict__ b2,
                                                     float* __restrict__ out){
    __shared__ _Float16 hfrag[2][4][16][32];  // 8 KB, MFMA-A fragment layout, dbuf
    __shared__ float hp_sh[4][3][4][32];      // [wave][gate][seq(reg)][hf*16+col] : b32 conflict-free
    __shared__ float h_f32[4][132];           // for head

    int tid  = threadIdx.x;
    int lane = tid & 63, wv = tid >> 6;
    int col  = lane & 15, quad = lane >> 4;
    int row0 = blockIdx.x * 4;

    for (int i = tid; i < 2*4*16*32; i += 256) ((_Float16*)hfrag)[i] = (_Float16)0.0f;

    // B fragments: 3 gates x 2 halves x 4 kq; n = g*128 + wv*32 + half*16 + col
    f16x8 bfr[3][2][4];
    #pragma unroll
    for (int g = 0; g < 3; ++g){
        #pragma unroll
        for (int hf = 0; hf < 2; ++hf){
            int n = g*128 + wv*32 + hf*16 + col;
            #pragma unroll
            for (int kq = 0; kq < 4; ++kq)
                bfr[g][hf][kq] = *(const f16x8*)&whh16[(size_t)n*HH + kq*32 + quad*8];
        }
    }

    int u  = lane & 31;
    int cc = wv*32 + u;
    int sb = lane >> 5;   // seq = j*2 + sb
    float bh0 = b_hh[cc], bh1 = b_hh[128 + cc], bh2 = b_hh[256 + cc];

    float hcur[2] = {0.0f, 0.0f};

    // 10-day register buffer; all indices static inside the unrolled cs loop
    const _Float16* xbase0 = XP + (size_t)(row0 + sb)*G3 + cc;       // seq j=0
    const _Float16* xbase1 = XP + (size_t)(row0 + 2 + sb)*G3 + cc;   // seq j=1
    const size_t DSTRIDE = (size_t)NN*G3;

    float xb[10][2][3];
    #pragma unroll
    for (int cs = 0; cs < 10; ++cs){
        const _Float16* b0 = xbase0 + (size_t)cs*DSTRIDE;
        const _Float16* b1 = xbase1 + (size_t)cs*DSTRIDE;
        xb[cs][0][0] = (float)b0[0]; xb[cs][0][1] = (float)b0[128]; xb[cs][0][2] = (float)b0[256];
        xb[cs][1][0] = (float)b1[0]; xb[cs][1][1] = (float)b1[128]; xb[cs][1][2] = (float)b1[256];
    }
    __syncthreads();

    #pragma unroll 1
    for (int chunk = 0; chunk < 6; ++chunk){
        #pragma unroll
        for (int cs = 0; cs < 10; ++cs){
            int d = chunk*10 + cs;
            int p = d & 1;
            // consume this step's inputs into locals
            float xcur[2][3];
            #pragma unroll
            for (int j = 0; j < 2; ++j){
                xcur[j][0] = xb[cs][j][0];
                xcur[j][1] = xb[cs][j][1];
                xcur[j][2] = xb[cs][j][2];
            }
            // at the last step of a chunk, refill the whole buffer for the next chunk;
            // these loads drain once at this step's barrier (~900 cyc / 10 steps)
            if (cs == 9 && chunk < 5){
                size_t off = (size_t)(chunk + 1)*10*DSTRIDE;
                #pragma unroll
                for (int c2 = 0; c2 < 10; ++c2){
                    const _Float16* b0 = xbase0 + off + (size_t)c2*DSTRIDE;
                    const _Float16* b1 = xbase1 + off + (size_t)c2*DSTRIDE;
                    xb[c2][0][0] = (float)b0[0]; xb[c2][0][1] = (float)b0[128]; xb[c2][0][2] = (float)b0[256];
                    xb[c2][1][0] = (float)b1[0]; xb[c2][1][1] = (float)b1[128]; xb[c2][1][2] = (float)b1[256];
                }
            }
            // A fragments from h (written at step d-1 into buffer p)
            f16x8 a[4];
            #pragma unroll
            for (int kq = 0; kq < 4; ++kq)
                a[kq] = *(const f16x8*)&hfrag[p][kq][col][quad*8];
            #pragma unroll
            for (int g = 0; g < 3; ++g){
                #pragma unroll
                for (int hf = 0; hf < 2; ++hf){
                    f32x4 c = {0.0f, 0.0f, 0.0f, 0.0f};
                    #pragma unroll
                    for (int kq = 0; kq < 4; ++kq)
                        c = __builtin_amdgcn_mfma_f32_16x16x32_f16(a[kq], bfr[g][hf][kq], c, 0, 0, 0);
                    if (quad == 0){
                        #pragma unroll
                        for (int reg = 0; reg < 4; ++reg)
                            hp_sh[wv][g][reg][hf*16 + col] = c[reg];
                    }
                }
            }
            // gates: same-wave LDS dependency only (no barrier)
            #pragma unroll
            for (int j = 0; j < 2; ++j){
                int seq = j*2 + sb;
                float hr = hp_sh[wv][0][seq][u] + bh0;
                float hz = hp_sh[wv][1][seq][u] + bh1;
                float hn = hp_sh[wv][2][seq][u] + bh2;
                float r  = sigmoidf_(xcur[j][0] + hr);
                float z  = sigmoidf_(xcur[j][1] + hz);
                float n  = tanhf_(xcur[j][2] + r*hn);
                float hnew = (1.0f - z)*n + z*hcur[j];
                hcur[j] = hnew;
                hfrag[1 - p][wv][seq][u] = (_Float16)hnew;
            }
            __syncthreads();
        }
    }

    #pragma unroll
    for (int j = 0; j < 2; ++j){
        int seq = j*2 + sb;
        h_f32[seq][cc] = hcur[j];
    }
    __syncthreads();

    if (tid < 64){
        int c2 = tid;
        #pragma unroll 1
        for (int r = 0; r < 4; ++r){
            float a0 = 0.0f, a1 = 0.0f;
            #pragma unroll 8
            for (int k = 0; k < 64; ++k){
                a0 = fmaf(h_f32[r][k],      w1[k*64 + c2],        a0);
                a1 = fmaf(h_f32[r][64 + k], w1[(64 + k)*64 + c2], a1);
            }
            float hid = fmaxf(a0 + a1 + b1[c2], 0.0f);
            float o = hid * w2[c2];
            #pragma unroll
            for (int off = 1; off < 64; off <<= 1) o += __shfl_xor(o, off, 64);
            if (c2 == 0) out[row0 + r] = o + b2[0];
        }
    }
}

extern "C" void kernel_launch(void* const* d_in, const int* in_sizes, int n_in,
                              void* d_out, int out_size, void* d_ws, size_t ws_size,
                              hipStream_t stream) {
    const float* x    = (const float*)d_in[0];
    const int*   mask = (const int*)d_in[1];
    const float* wq   = (const float*)d_in[2];
    const float* bq   = (const float*)d_in[3];
    const float* wk   = (const float*)d_in[4];
    const float* bk   = (const float*)d_in[5];
    const float* wv   = (const float*)d_in[6];
    const float* bv   = (const float*)d_in[7];
    const float* ln_g = (const float*)d_in[8];
    const float* ln_b = (const float*)d_in[9];
    const float* w_ih = (const float*)d_in[10];
    const float* w_hh = (const float*)d_in[11];
    const float* b_ih = (const float*)d_in[12];
    const float* b_hh = (const float*)d_in[13];
    const float* w1   = (const float*)d_in[14];
    const float* b1   = (const float*)d_in[15];
    const float* w2   = (const float*)d_in[16];
    const float* b2   = (const float*)d_in[17];

    float* ws = (float*)d_ws;
    // phase 1 (f32 index units):
    _Float16* Qh  = (_Float16*)ws;                    // f16 [0, 3,932,160)
    _Float16* Kh  = (_Float16*)(ws + 3932160);        // f16 [3,932,160, 7,864,320)
    float*    V   = ws + 7864320;                     // f32 [7,864,320, 15,728,640)
    // phase 2: XP aliases the dead Q/K/V region
    _Float16* XP  = (_Float16*)ws;                    // f16 [0, 23,592,960)
    float* market = ws + 23592960;                    //    15,360 f32
    _Float16* wf16 = (_Float16*)(ws + 23608320);      //    86,016 f16
    _Float16* wqkv = (_Float16*)(ws + 23651328);      //    30,720 f16
    _Float16* whh16= (_Float16*)(ws + 23666688);      //    49,152 f16
    // total ~94.8 MB

    prep_kernel<<<648, 256, 0, stream>>>(w_ih, wq, wk, wv, w_hh, wf16, wqkv, whh16);
    qkv_kernel<<<1920, 256, 0, stream>>>(x, wqkv, bq, bk, bv, Qh, Kh, V);
    attn_kernel<<<240, 512, 0, stream>>>(Qh, Kh, mask, V, market);
    xproj_kernel<<<1920, 512, 0, stream>>>(x, market, ln_g, ln_b, wf16, b_ih, XP);
    gru_kernel<<<512, 256, 0, stream>>>(XP, whh16, b_hh, w1, b1, w2, b2, (float*)d_out);
}